// Round 3
// baseline (434.972 us; speedup 1.0000x reference)
//
#include <hip/hip_runtime.h>
#include <hip/hip_bf16.h>

typedef unsigned short u16;
typedef unsigned int   u32;
typedef __bf16 bf16x8 __attribute__((ext_vector_type(8)));
typedef float  f32x4  __attribute__((ext_vector_type(4)));

#define NB 4
#define T_ 2048
#define D_ 1024
#define H_ 16
#define DH 64
#define M_ (NB * T_)   // 8192 rows
#define PSTR 72        // padded LDS row stride (elements) for 64-wide tiles

__device__ __forceinline__ float bf2f(u16 u) {
    union { u32 i; float f; } v; v.i = ((u32)u) << 16; return v.f;
}
// native RTNE cast (compiler emits v_cvt_pk_bf16_f32 / single cvt, ~1 op)
__device__ __forceinline__ u16 f2bf(float f) {
    __bf16 b = (__bf16)f;
    union { __bf16 b; u16 u; } v; v.b = b; return v.u;
}

// async global->LDS, 16B per lane; lds base must be wave-uniform
__device__ __forceinline__ void gl_lds16(const u16* g, u16* l) {
    __builtin_amdgcn_global_load_lds((const __attribute__((address_space(1))) void*)g,
                                     (__attribute__((address_space(3))) void*)l,
                                     16, 0, 0);
}

// ---------------------------------------------------------- dtype detector
__device__ __forceinline__ int detect_f32(const u16* p) {
    int weird = 0;
    const int lane = threadIdx.x & 63;
    #pragma unroll
    for (int i = 0; i < 4; ++i) {
        const u16 u = p[lane * 4 + i];
        const int e = (u >> 7) & 0xFF;
        weird += (e == 0xFF || (e >= 0x01 && e <= 0x3F) || (e >= 0xC0 && e <= 0xFE));
    }
    #pragma unroll
    for (int off = 32; off; off >>= 1) weird += __shfl_xor(weird, off);
    return weird >= 16;
}

// int32/int64-tolerant sequence-length read
__device__ __forceinline__ int read_len(const void* raw, int b) {
    const int* a32 = (const int*)raw;
    bool ok32 = true;
    #pragma unroll
    for (int i = 0; i < NB; ++i) {
        const int v = a32[i];
        if (v < 1 || v > T_) ok32 = false;
    }
    int v = ok32 ? a32[b] : (int)((const long long*)raw)[b];
    return min(max(v, 1), T_);
}

// ---------------------------------------------------------------- LayerNorm
__global__ __launch_bounds__(256) void ln_kernel(const void* __restrict__ xraw,
                                                 const void* __restrict__ graw,
                                                 const void* __restrict__ braw,
                                                 u16* __restrict__ h) {
    const int row = blockIdx.x;
    const int tid = threadIdx.x;
    const int isf = detect_f32((const u16*)xraw);

    float xv[4];
    if (isf) {
        const float* xr = (const float*)xraw + (size_t)row * D_;
        *(float4*)xv = *(const float4*)&xr[tid * 4];
    } else {
        const u16* xr = (const u16*)xraw + (size_t)row * D_;
        u16 loc[4] __attribute__((aligned(8)));
        *(uint2*)loc = *(const uint2*)&xr[tid * 4];
        #pragma unroll
        for (int i = 0; i < 4; ++i) xv[i] = bf2f(loc[i]);
    }

    float s = xv[0] + xv[1] + xv[2] + xv[3];
    float q = xv[0]*xv[0] + xv[1]*xv[1] + xv[2]*xv[2] + xv[3]*xv[3];

    #pragma unroll
    for (int off = 32; off; off >>= 1) {
        s += __shfl_xor(s, off);
        q += __shfl_xor(q, off);
    }
    __shared__ float red[8];
    const int wave = tid >> 6, lane = tid & 63;
    if (lane == 0) { red[wave] = s; red[4 + wave] = q; }
    __syncthreads();
    s = red[0] + red[1] + red[2] + red[3];
    q = red[4] + red[5] + red[6] + red[7];

    const float mean = s * (1.0f / D_);
    const float var  = q * (1.0f / D_) - mean * mean;
    const float rs   = rsqrtf(var + 1e-5f);

    u16 o[4] __attribute__((aligned(8)));
    #pragma unroll
    for (int i = 0; i < 4; ++i) {
        const int c = tid * 4 + i;
        const float gv = isf ? ((const float*)graw)[c] : bf2f(((const u16*)graw)[c]);
        const float bv = isf ? ((const float*)braw)[c] : bf2f(((const u16*)braw)[c]);
        o[i] = f2bf((xv[i] - mean) * rs * gv + bv);
    }
    *(uint2*)&h[(size_t)row * D_ + tid * 4] = *(uint2*)o;
}

// ------------------------------------------------- weight transpose+convert
__global__ __launch_bounds__(256) void wconv_kernel(const void* __restrict__ Wraw,
                                                    u16* __restrict__ Wt) {
    __shared__ u16 tile[64][PSTR];
    const int isf = detect_f32((const u16*)Wraw);
    const int n0 = blockIdx.x * 64;
    const int k0 = blockIdx.y * 64;
    const int tid = threadIdx.x;
    const int tr  = tid >> 2;          // 0..63
    const int tc  = (tid & 3) * 16;    // 0,16,32,48

    if (isf) {
        const float* W = (const float*)Wraw;
        #pragma unroll
        for (int i = 0; i < 16; ++i)
            tile[tc + i][tr] = f2bf(W[(size_t)(k0 + tr) * D_ + n0 + tc + i]);
    } else {
        const u16* W = (const u16*)Wraw;
        #pragma unroll
        for (int i = 0; i < 16; ++i)
            tile[tc + i][tr] = W[(size_t)(k0 + tr) * D_ + n0 + tc + i];
    }
    __syncthreads();
    *(uint4*)&Wt[(size_t)(n0 + tr) * D_ + k0 + tc]     = *(uint4*)&tile[tr][tc];
    *(uint4*)&Wt[(size_t)(n0 + tr) * D_ + k0 + tc + 8] = *(uint4*)&tile[tr][tc + 8];
}

// ---------------------------------------------------------------- RoPE table
// tab[t*32 + i] = {cos(t * 10000^(-i/32)), sin(...)}   (accurate library trig)
__global__ __launch_bounds__(256) void rope_kernel(float2* __restrict__ tab) {
    const int gid = blockIdx.x * 256 + threadIdx.x;   // 0..65535
    const int t = gid >> 5, i = gid & 31;
    const float inv = exp2f(-(float)i * 0.41524101186092f);
    const float ang = (float)t * inv;
    float sv, cv;
    sincosf(ang, &sv, &cv);
    tab[gid] = make_float2(cv, sv);
}

// --------------------------------------------------- V transpose (per head)
// vtmp (M, D) row-major -> vt (N, H, DH, T)
__global__ __launch_bounds__(256) void vtrans_kernel(const u16* __restrict__ vtmp,
                                                     u16* __restrict__ vt) {
    __shared__ u16 tile[64][PSTR];
    const int bh = blockIdx.y;
    const int b  = bh >> 4;
    const int hh = bh & 15;
    const int t0 = blockIdx.x * 64;
    const int tid = threadIdx.x;
    const int tr  = tid >> 2;          // 0..63
    const int tc  = (tid & 3) * 16;

    #pragma unroll
    for (int i = 0; i < 16; ++i)   // tile[d][t]
        tile[tc + i][tr] = vtmp[(size_t)(b * T_ + t0 + tr) * D_ + hh * DH + tc + i];
    __syncthreads();
    u16* dst = vt + (size_t)bh * DH * T_ + (size_t)tr * T_ + t0;
    *(uint4*)&dst[tc]     = *(uint4*)&tile[tr][tc];
    *(uint4*)&dst[tc + 8] = *(uint4*)&tile[tr][tc + 8];
}

// ---------------------------------------------------------------- fused QKV GEMM
// 128x128 tile over fused N=3072 (wtq|wtk|wtv contiguous). All outputs
// ROW-MAJOR (M, D). Q,K: table-based RoPE fused. V -> vtmp (transposed later).
__global__ __launch_bounds__(256) void qkv_kernel(const u16* __restrict__ A,
                                                  const u16* __restrict__ Wt3,
                                                  const void* __restrict__ Braw,
                                                  const void* __restrict__ bqr,
                                                  const void* __restrict__ bkr,
                                                  const void* __restrict__ bvr,
                                                  u16* __restrict__ qo,
                                                  u16* __restrict__ ko,
                                                  u16* __restrict__ vo,
                                                  const float2* __restrict__ tab) {
    __shared__ __align__(16) u16 As[128 * 32];
    __shared__ __align__(16) u16 Bs[128 * 32];

    const int tid   = threadIdx.x;
    const int wave  = tid >> 6;
    const int lane  = tid & 63;
    const int quad  = lane >> 4;
    const int lr    = lane & 15;
    const int ntile = blockIdx.x * 128;      // 0..2944
    const int mtile = blockIdx.y * 128;
    const int seg   = ntile >> 10;           // 0=Q 1=K 2=V

    const int isf = detect_f32((const u16*)Braw);

    const int srow = wave * 32 + (lane >> 2);
    const int scol = (lane & 3) * 8;
    const u16* aptr0 = A   + (size_t)(mtile + srow) * D_ + scol;
    const u16* aptr1 = A   + (size_t)(mtile + srow + 16) * D_ + scol;
    const u16* bptr0 = Wt3 + (size_t)(ntile + srow) * D_ + scol;
    const u16* bptr1 = Wt3 + (size_t)(ntile + srow + 16) * D_ + scol;
    u16* alds0 = As + wave * 1024;
    u16* alds1 = As + wave * 1024 + 512;
    u16* blds0 = Bs + wave * 1024;
    u16* blds1 = Bs + wave * 1024 + 512;

    const int mbase = (wave >> 1) * 64;
    const int nbase = (wave & 1) * 64;

    f32x4 acc[4][4];
    #pragma unroll
    for (int m = 0; m < 4; ++m)
        #pragma unroll
        for (int n = 0; n < 4; ++n)
            acc[m][n] = (f32x4){0.f, 0.f, 0.f, 0.f};

    for (int k0 = 0; k0 < D_; k0 += 32) {
        gl_lds16(aptr0 + k0, alds0);
        gl_lds16(aptr1 + k0, alds1);
        gl_lds16(bptr0 + k0, blds0);
        gl_lds16(bptr1 + k0, blds1);
        __syncthreads();

        bf16x8 af[4], bfr[4];
        #pragma unroll
        for (int m = 0; m < 4; ++m)
            af[m] = *(const bf16x8*)&As[(mbase + m * 16 + lr) * 32 + quad * 8];
        #pragma unroll
        for (int n = 0; n < 4; ++n)
            bfr[n] = *(const bf16x8*)&Bs[(nbase + n * 16 + lr) * 32 + quad * 8];
        #pragma unroll
        for (int m = 0; m < 4; ++m)
            #pragma unroll
            for (int n = 0; n < 4; ++n)
                acc[m][n] = __builtin_amdgcn_mfma_f32_16x16x32_bf16(af[m], bfr[n], acc[m][n], 0, 0, 0);

        __syncthreads();
    }

    const void* biasraw = (seg == 0) ? bqr : (seg == 1) ? bkr : bvr;
    u16* out            = (seg == 0) ? qo  : (seg == 1) ? ko  : vo;
    const int nloc = (ntile & 1023) + nbase;

    #pragma unroll
    for (int m = 0; m < 4; ++m) {
        #pragma unroll
        for (int n = 0; n < 4; ++n) {
            const int ncl = nloc + n * 16 + lr;       // 0..1023 within segment
            const float bv = isf ? ((const float*)biasraw)[ncl]
                                 : bf2f(((const u16*)biasraw)[ncl]);
            #pragma unroll
            for (int r = 0; r < 4; ++r) {
                const int mrow = mtile + mbase + m * 16 + quad * 4 + r;
                float v = acc[m][n][r] + bv;
                if (seg < 2) {
                    const float other = __shfl_xor(v, 1);
                    const int d = ncl & (DH - 1);
                    const int t = mrow & (T_ - 1);
                    const float2 cs = tab[t * 32 + (d >> 1)];
                    v = (d & 1) ? (other * cs.y + v * cs.x) : (v * cs.x - other * cs.y);
                }
                out[(size_t)mrow * D_ + ncl] = f2bf(v);
            }
        }
    }
}

// ---------------------------------------------------------------- GEMM (m97 structure)
// mode 0: row-major store to out (format follows weight dtype)
// mode 1: scatter V TRANSPOSED (N,H,DH,T)            [fallback path only]
// mode 2: scatter (N,H,T,DH) + RoPE (Q,K), sincosf   [fallback path only]
__global__ __launch_bounds__(256) void gemm128_kernel(const u16* __restrict__ A,
                                                      const u16* __restrict__ Bt,
                                                      const void* __restrict__ Braw,
                                                      const void* __restrict__ biasraw,
                                                      void* __restrict__ out,
                                                      const int mode) {
    __shared__ __align__(16) u16 As[128 * 32];
    __shared__ __align__(16) u16 Bs[128 * 32];

    const int tid   = threadIdx.x;
    const int wave  = tid >> 6;
    const int lane  = tid & 63;
    const int quad  = lane >> 4;
    const int lr    = lane & 15;
    const int ntile = blockIdx.x * 128;
    const int mtile = blockIdx.y * 128;

    const int isf = detect_f32((const u16*)Braw);

    const int srow = wave * 32 + (lane >> 2);
    const int scol = (lane & 3) * 8;
    const u16* aptr0 = A  + (size_t)(mtile + srow) * D_ + scol;
    const u16* aptr1 = A  + (size_t)(mtile + srow + 16) * D_ + scol;
    const u16* bptr0 = Bt + (size_t)(ntile + srow) * D_ + scol;
    const u16* bptr1 = Bt + (size_t)(ntile + srow + 16) * D_ + scol;
    u16* alds0 = As + wave * 1024;
    u16* alds1 = As + wave * 1024 + 512;
    u16* blds0 = Bs + wave * 1024;
    u16* blds1 = Bs + wave * 1024 + 512;

    const int mbase = (wave >> 1) * 64;
    const int nbase = (wave & 1) * 64;

    f32x4 acc[4][4];
    #pragma unroll
    for (int m = 0; m < 4; ++m)
        #pragma unroll
        for (int n = 0; n < 4; ++n)
            acc[m][n] = (f32x4){0.f, 0.f, 0.f, 0.f};

    for (int k0 = 0; k0 < D_; k0 += 32) {
        gl_lds16(aptr0 + k0, alds0);
        gl_lds16(aptr1 + k0, alds1);
        gl_lds16(bptr0 + k0, blds0);
        gl_lds16(bptr1 + k0, blds1);
        __syncthreads();

        bf16x8 af[4], bfr[4];
        #pragma unroll
        for (int m = 0; m < 4; ++m)
            af[m] = *(const bf16x8*)&As[(mbase + m * 16 + lr) * 32 + quad * 8];
        #pragma unroll
        for (int n = 0; n < 4; ++n)
            bfr[n] = *(const bf16x8*)&Bs[(nbase + n * 16 + lr) * 32 + quad * 8];
        #pragma unroll
        for (int m = 0; m < 4; ++m)
            #pragma unroll
            for (int n = 0; n < 4; ++n)
                acc[m][n] = __builtin_amdgcn_mfma_f32_16x16x32_bf16(af[m], bfr[n], acc[m][n], 0, 0, 0);

        __syncthreads();
    }

    #pragma unroll
    for (int m = 0; m < 4; ++m) {
        #pragma unroll
        for (int n = 0; n < 4; ++n) {
            const int ncol = ntile + nbase + n * 16 + lr;
            const float bv = isf ? ((const float*)biasraw)[ncol]
                                 : bf2f(((const u16*)biasraw)[ncol]);
            #pragma unroll
            for (int r = 0; r < 4; ++r) {
                const int mrow = mtile + mbase + m * 16 + quad * 4 + r;
                float v = acc[m][n][r] + bv;
                if (mode == 2) {
                    const float other = __shfl_xor(v, 1);
                    const int d = ncol & (DH - 1);
                    const int t = mrow & (T_ - 1);
                    const int i = d >> 1;
                    const float inv = exp2f(-(float)i * 0.41524101186092f);
                    const float ang = (float)t * inv;
                    float sv, cv;
                    __sincosf(ang, &sv, &cv);
                    v = (d & 1) ? (other * sv + v * cv) : (v * cv - other * sv);
                }
                const int d  = ncol & (DH - 1);
                const int hh = ncol >> 6;
                const int t  = mrow & (T_ - 1);
                const int bb = mrow >> 11;
                if (mode == 0) {
                    if (isf) ((float*)out)[(size_t)mrow * D_ + ncol] = v;
                    else     ((u16*)out)[(size_t)mrow * D_ + ncol] = f2bf(v);
                } else if (mode == 1) {
                    ((u16*)out)[(((size_t)(bb * H_ + hh) * DH) + d) * T_ + t] = f2bf(v);
                } else {
                    ((u16*)out)[(((size_t)(bb * H_ + hh) * T_) + t) * DH + d] = f2bf(v);
                }
            }
        }
    }
}

// ---------------------------------------------------------------- GEMM (no-wt fallback)
__global__ __launch_bounds__(256) void gemm_kernel(const u16* __restrict__ A,
                                                   const void* __restrict__ Braw,
                                                   const void* __restrict__ biasraw,
                                                   void* __restrict__ out,
                                                   const int mode) {
    __shared__ __align__(16) u16 As[128 * 32];
    __shared__ __align__(16) u16 Bs[64 * 32];

    const int tid   = threadIdx.x;
    const int ntile = blockIdx.x * 64;
    const int mtile = blockIdx.y * 128;
    const int wave  = tid >> 6;
    const int lane  = tid & 63;
    const int quad  = lane >> 4;
    const int lr    = lane & 15;

    const int isf = detect_f32((const u16*)Braw);
    const float* Bf = (const float*)Braw;
    const u16*   Bu = (const u16*)Braw;

    f32x4 acc[2][4];
    #pragma unroll
    for (int s = 0; s < 2; ++s)
        #pragma unroll
        for (int n = 0; n < 4; ++n)
            acc[s][n] = (f32x4){0.f, 0.f, 0.f, 0.f};

    const int ar  = tid >> 1;
    const int akb = (tid & 1) * 16;
    const int bn  = tid & 63;
    const int bkb = (tid >> 6) * 8;
    const u16* Arow = A + (size_t)(mtile + ar) * D_ + akb;
    const size_t bcol0 = (size_t)bkb * D_ + ntile + bn;

    for (int k0 = 0; k0 < D_; k0 += 32) {
        *(uint4*)&As[ar * 32 + akb]     = *(const uint4*)(Arow + k0);
        *(uint4*)&As[ar * 32 + akb + 8] = *(const uint4*)(Arow + k0 + 8);
        {
            u16 tmp[8] __attribute__((aligned(16)));
            if (isf) {
                #pragma unroll
                for (int j = 0; j < 8; ++j) tmp[j] = f2bf(Bf[bcol0 + (size_t)(k0 + j) * D_]);
            } else {
                #pragma unroll
                for (int j = 0; j < 8; ++j) tmp[j] = Bu[bcol0 + (size_t)(k0 + j) * D_];
            }
            *(uint4*)&Bs[bn * 32 + bkb] = *(uint4*)tmp;
        }
        __syncthreads();

        const int mbase = wave * 32;
        bf16x8 af0 = *(const bf16x8*)&As[(mbase +      lr) * 32 + quad * 8];
        bf16x8 af1 = *(const bf16x8*)&As[(mbase + 16 + lr) * 32 + quad * 8];
        #pragma unroll
        for (int nt = 0; nt < 4; ++nt) {
            bf16x8 bf = *(const bf16x8*)&Bs[(nt * 16 + lr) * 32 + quad * 8];
            acc[0][nt] = __builtin_amdgcn_mfma_f32_16x16x32_bf16(af0, bf, acc[0][nt], 0, 0, 0);
            acc[1][nt] = __builtin_amdgcn_mfma_f32_16x16x32_bf16(af1, bf, acc[1][nt], 0, 0, 0);
        }
        __syncthreads();
    }

    #pragma unroll
    for (int s2 = 0; s2 < 2; ++s2) {
        #pragma unroll
        for (int nt = 0; nt < 4; ++nt) {
            const int ncol = ntile + nt * 16 + lr;
            const float bv = isf ? ((const float*)biasraw)[ncol]
                                 : bf2f(((const u16*)biasraw)[ncol]);
            #pragma unroll
            for (int r = 0; r < 4; ++r) {
                const int mrow = mtile + wave * 32 + s2 * 16 + quad * 4 + r;
                float v = acc[s2][nt][r] + bv;
                if (mode == 2) {
                    const float other = __shfl_xor(v, 1);
                    const int d = ncol & (DH - 1);
                    const int t = mrow & (T_ - 1);
                    const int i = d >> 1;
                    const float inv = exp2f(-(float)i * 0.41524101186092f);
                    const float ang = (float)t * inv;
                    const float cv = cosf(ang), sv = sinf(ang);
                    v = (d & 1) ? (other * sv + v * cv) : (v * cv - other * sv);
                }
                const int d  = ncol & (DH - 1);
                const int hh = ncol >> 6;
                const int t  = mrow & (T_ - 1);
                const int bb = mrow >> 11;
                if (mode == 0) {
                    if (isf) ((float*)out)[(size_t)mrow * D_ + ncol] = v;
                    else     ((u16*)out)[(size_t)mrow * D_ + ncol] = f2bf(v);
                } else if (mode == 1) {
                    ((u16*)out)[(((size_t)(bb * H_ + hh) * DH) + d) * T_ + t] = f2bf(v);
                } else {
                    ((u16*)out)[(((size_t)(bb * H_ + hh) * T_) + t) * DH + d] = f2bf(v);
                }
            }
        }
    }
}

// ---------------------------------------------------------------- attention
// MFMA flash attention, FIXED-MAX softmax (cap-tanh folded):
//   p = exp2(-60*log2e / (z+1)), z = exp2(s*log2e/120)
// ONE barrier per K-tile: the P tile is wave-private (softmax writes rows
// wave*16..+15, PV A-frag reads exactly those rows), so no barrier between
// softmax and PV. Double-buffered K/V LDS + reg-staged async prefetch.
// rowmajor=1: Q/K are (M, D) row-major; rowmajor=0: (N,H,T,DH).
__global__ __launch_bounds__(256) void attn_kernel(const u16* __restrict__ Q,
                                                   const u16* __restrict__ K,
                                                   const u16* __restrict__ Vt,
                                                   const void* __restrict__ lensraw,
                                                   u16* __restrict__ ctx,
                                                   const int rowmajor) {
    __shared__ __align__(16) u16 Ps[64 * PSTR];        // Q staging, then P tile
    __shared__ __align__(16) u16 Ks[2][64 * PSTR];
    __shared__ __align__(16) u16 Vts[2][64 * PSTR];    // [dim][key]

    const int tid  = threadIdx.x;
    const int wave = tid >> 6;
    const int lane = tid & 63;
    const int quad = lane >> 4;
    const int lr   = lane & 15;
    const int bh   = blockIdx.y;
    const int qs   = blockIdx.x * 64;
    const int b    = bh >> 4;
    const int hh   = bh & 15;
    const int len  = read_len(lensraw, b);

    const size_t qkstride = rowmajor ? (size_t)D_ : (size_t)DH;
    const size_t qkoff    = rowmajor ? ((size_t)b * T_ * D_ + hh * DH)
                                     : ((size_t)bh * T_ * DH);
    const u16* Qp = Q + qkoff;
    const u16* Kp = K + qkoff;
    const u16* Vb = Vt + (size_t)bh * DH * T_;

    const int srow = tid >> 2;
    const int scb  = (tid & 3) * 16;

    // Q staging (wave-private rows) + K/V tile 0
    *(uint4*)&Ps[srow * PSTR + scb]     = *(const uint4*)&Qp[(size_t)(qs + srow) * qkstride + scb];
    *(uint4*)&Ps[srow * PSTR + scb + 8] = *(const uint4*)&Qp[(size_t)(qs + srow) * qkstride + scb + 8];
    {
        uint4 k0 = *(const uint4*)&Kp[(size_t)srow * qkstride + scb];
        uint4 k1 = *(const uint4*)&Kp[(size_t)srow * qkstride + scb + 8];
        uint4 v0 = *(const uint4*)&Vb[(size_t)srow * T_ + scb];
        uint4 v1 = *(const uint4*)&Vb[(size_t)srow * T_ + scb + 8];
        *(uint4*)&Ks[0][srow * PSTR + scb]      = k0;
        *(uint4*)&Ks[0][srow * PSTR + scb + 8]  = k1;
        *(uint4*)&Vts[0][srow * PSTR + scb]     = v0;
        *(uint4*)&Vts[0][srow * PSTR + scb + 8] = v1;
    }
    __syncthreads();
    const bf16x8 qa0 = *(const bf16x8*)&Ps[(wave * 16 + lr) * PSTR + quad * 8];
    const bf16x8 qa1 = *(const bf16x8*)&Ps[(wave * 16 + lr) * PSTR + 32 + quad * 8];

    f32x4 acc[4];
    float l_loc[4] = {0.f, 0.f, 0.f, 0.f};
    #pragma unroll
    for (int nt = 0; nt < 4; ++nt) acc[nt] = (f32x4){0.f, 0.f, 0.f, 0.f};

    const int smax = min(qs + 63, len - 1);
    const int ktn  = smax / 64 + 1;
    const int prow = wave * 16 + quad * 4;

    const float C1 = 1.44269504f / 120.0f;   // log2e / 120
    const float C2 = -60.0f * 1.44269504f;   // -60 * log2e

    int buf = 0;
    uint4 kr0, kr1, vr0, vr1;
    for (int kt = 0; kt < ktn; ++kt) {
        const int ks = kt * 64;
        const bool havenext = (kt + 1 < ktn);

        // async prefetch next tile into regs (hides under QK+SM+PV)
        if (havenext) {
            const int ns = ks + 64;
            kr0 = *(const uint4*)&Kp[(size_t)(ns + srow) * qkstride + scb];
            kr1 = *(const uint4*)&Kp[(size_t)(ns + srow) * qkstride + scb + 8];
            vr0 = *(const uint4*)&Vb[(size_t)srow * T_ + ns + scb];
            vr1 = *(const uint4*)&Vb[(size_t)srow * T_ + ns + scb + 8];
        }

        // QK^T
        f32x4 s[4];
        #pragma unroll
        for (int nt = 0; nt < 4; ++nt) s[nt] = (f32x4){0.f, 0.f, 0.f, 0.f};
        __builtin_amdgcn_s_setprio(1);
        #pragma unroll
        for (int nt = 0; nt < 4; ++nt) {
            bf16x8 kb0 = *(const bf16x8*)&Ks[buf][(nt * 16 + lr) * PSTR + quad * 8];
            bf16x8 kb1 = *(const bf16x8*)&Ks[buf][(nt * 16 + lr) * PSTR + 32 + quad * 8];
            s[nt] = __builtin_amdgcn_mfma_f32_16x16x32_bf16(qa0, kb0, s[nt], 0, 0, 0);
            s[nt] = __builtin_amdgcn_mfma_f32_16x16x32_bf16(qa1, kb1, s[nt], 0, 0, 0);
        }
        __builtin_amdgcn_s_setprio(0);

        // fixed-max softmax; masking only on diagonal / len-boundary tiles
        const bool need_mask = (ks == qs) || (ks + 63 >= len);
        if (!need_mask) {
            #pragma unroll
            for (int r = 0; r < 4; ++r) {
                #pragma unroll
                for (int nt = 0; nt < 4; ++nt) {
                    const float z = exp2f(s[nt][r] * C1);
                    const float p = exp2f(C2 * __builtin_amdgcn_rcpf(z + 1.0f));
                    l_loc[r] += p;
                    Ps[(prow + r) * PSTR + nt * 16 + lr] = f2bf(p);
                }
            }
        } else {
            #pragma unroll
            for (int r = 0; r < 4; ++r) {
                const int trow = qs + prow + r;
                #pragma unroll
                for (int nt = 0; nt < 4; ++nt) {
                    const float z = exp2f(s[nt][r] * C1);
                    float p = exp2f(C2 * __builtin_amdgcn_rcpf(z + 1.0f));
                    const int col = ks + nt * 16 + lr;
                    p = (col > trow || col >= len) ? 0.f : p;
                    l_loc[r] += p;
                    Ps[(prow + r) * PSTR + nt * 16 + lr] = f2bf(p);
                }
            }
        }
        // NO barrier: Ps rows are wave-private (compiler orders same-wave lds)

        // PV
        bf16x8 pa0 = *(const bf16x8*)&Ps[(wave * 16 + lr) * PSTR + quad * 8];
        bf16x8 pa1 = *(const bf16x8*)&Ps[(wave * 16 + lr) * PSTR + 32 + quad * 8];
        __builtin_amdgcn_s_setprio(1);
        #pragma unroll
        for (int nt = 0; nt < 4; ++nt) {
            bf16x8 vb0 = *(const bf16x8*)&Vts[buf][(nt * 16 + lr) * PSTR + quad * 8];
            bf16x8 vb1 = *(const bf16x8*)&Vts[buf][(nt * 16 + lr) * PSTR + 32 + quad * 8];
            acc[nt] = __builtin_amdgcn_mfma_f32_16x16x32_bf16(pa0, vb0, acc[nt], 0, 0, 0);
            acc[nt] = __builtin_amdgcn_mfma_f32_16x16x32_bf16(pa1, vb1, acc[nt], 0, 0, 0);
        }
        __builtin_amdgcn_s_setprio(0);

        // land prefetched tile in the other buffer
        if (havenext) {
            *(uint4*)&Ks[buf ^ 1][srow * PSTR + scb]      = kr0;
            *(uint4*)&Ks[buf ^ 1][srow * PSTR + scb + 8]  = kr1;
            *(uint4*)&Vts[buf ^ 1][srow * PSTR + scb]     = vr0;
            *(uint4*)&Vts[buf ^ 1][srow * PSTR + scb + 8] = vr1;
        }
        __syncthreads();   // single barrier: dbuf write/read ordering across waves
        buf ^= 1;
    }

    // epilogue: reduce l across the 16 lanes of each row group, write ctx
    #pragma unroll
    for (int r = 0; r < 4; ++r) {
        float l = l_loc[r];
        #pragma unroll
        for (int off = 1; off < 16; off <<= 1) l += __shfl_xor(l, off);
        const float invl = (l > 0.f) ? (1.0f / l) : 0.f;
        const int qrow = prow + r;
        #pragma unroll
        for (int nt = 0; nt < 4; ++nt) {
            ctx[(size_t)(b * T_ + qs + qrow) * D_ + hh * DH + nt * 16 + lr] =
                f2bf(acc[nt][r] * invl);
        }
    }
}

// ---------------------------------------------------------------- launch
extern "C" void kernel_launch(void* const* d_in, const int* in_sizes, int n_in,
                              void* d_out, int out_size, void* d_ws, size_t ws_size,
                              hipStream_t stream) {
    // ws layout: [h][q][k][vt : 16MB each][wtq|wtk|wtv|wto : 2MB each]
    //            [vtmp 16MB][rope table 512KB]
    u16* h = (u16*)d_ws;
    const size_t MD = (size_t)M_ * D_;
    const size_t WD = (size_t)D_ * D_;
    u16* q  = h + MD;
    u16* k  = q + MD;
    u16* vt = k + MD;
    const bool havewt  = ws_size >= (4 * MD + 4 * WD) * sizeof(u16);
    const bool havebig = ws_size >= (5 * MD + 4 * WD) * sizeof(u16)
                                    + (size_t)T_ * 32 * sizeof(float2);
    u16* wtq = havewt ? (vt + MD)  : nullptr;
    u16* wtk = havewt ? (wtq + WD) : nullptr;
    u16* wtv = havewt ? (wtk + WD) : nullptr;
    u16* wto = havewt ? (wtv + WD) : nullptr;
    u16* vtmp = havebig ? (wto + WD) : nullptr;
    float2* tab = havebig ? (float2*)(vtmp + MD) : nullptr;

    ln_kernel<<<M_, 256, 0, stream>>>(d_in[0], d_in[1], d_in[2], h);

    if (havebig) {
        dim3 wgrid(D_ / 64, D_ / 64);
        wconv_kernel<<<wgrid, 256, 0, stream>>>(d_in[3], wtq);
        wconv_kernel<<<wgrid, 256, 0, stream>>>(d_in[5], wtk);
        wconv_kernel<<<wgrid, 256, 0, stream>>>(d_in[7], wtv);
        wconv_kernel<<<wgrid, 256, 0, stream>>>(d_in[9], wto);
        rope_kernel<<<256, 256, 0, stream>>>(tab);

        qkv_kernel<<<dim3(3 * D_ / 128, M_ / 128), 256, 0, stream>>>(
            h, wtq, d_in[3], d_in[4], d_in[6], d_in[8], q, k, vtmp, tab);

        vtrans_kernel<<<dim3(T_ / 64, NB * H_), 256, 0, stream>>>(vtmp, vt);

        attn_kernel<<<dim3(T_ / 64, NB * H_), 256, 0, stream>>>(q, k, vt, d_in[13], h, 1);

        gemm128_kernel<<<dim3(D_ / 128, M_ / 128), 256, 0, stream>>>(
            h, wto, d_in[9], d_in[10], d_out, 0);
    } else if (havewt) {
        dim3 wgrid(D_ / 64, D_ / 64);
        wconv_kernel<<<wgrid, 256, 0, stream>>>(d_in[3], wtq);
        wconv_kernel<<<wgrid, 256, 0, stream>>>(d_in[5], wtk);
        wconv_kernel<<<wgrid, 256, 0, stream>>>(d_in[7], wtv);
        wconv_kernel<<<wgrid, 256, 0, stream>>>(d_in[9], wto);

        dim3 g128(D_ / 128, M_ / 128);
        gemm128_kernel<<<g128, 256, 0, stream>>>(h, wtq, d_in[3], d_in[4], q, 2);
        gemm128_kernel<<<g128, 256, 0, stream>>>(h, wtk, d_in[5], d_in[6], k, 2);
        gemm128_kernel<<<g128, 256, 0, stream>>>(h, wtv, d_in[7], d_in[8], vt, 1);

        attn_kernel<<<dim3(T_ / 64, NB * H_), 256, 0, stream>>>(q, k, vt, d_in[13], h, 0);

        gemm128_kernel<<<g128, 256, 0, stream>>>(h, wto, d_in[9], d_in[10], d_out, 0);
    } else {
        dim3 ggrid(D_ / 64, M_ / 128);
        gemm_kernel<<<ggrid, 256, 0, stream>>>(h, d_in[3], d_in[4], q, 2);
        gemm_kernel<<<ggrid, 256, 0, stream>>>(h, d_in[5], d_in[6], k, 2);
        gemm_kernel<<<ggrid, 256, 0, stream>>>(h, d_in[7], d_in[8], vt, 1);

        attn_kernel<<<dim3(T_ / 64, NB * H_), 256, 0, stream>>>(q, k, vt, d_in[13], h, 0);

        gemm_kernel<<<ggrid, 256, 0, stream>>>(h, d_in[9], d_in[10], d_out, 0);
    }
}

// Round 4
// 386.372 us; speedup vs baseline: 1.1258x; 1.1258x over previous
//
#include <hip/hip_runtime.h>
#include <hip/hip_bf16.h>

typedef unsigned short u16;
typedef unsigned int   u32;
typedef __bf16 bf16x8 __attribute__((ext_vector_type(8)));
typedef float  f32x4  __attribute__((ext_vector_type(4)));

#define NB 4
#define T_ 2048
#define D_ 1024
#define H_ 16
#define DH 64
#define M_ (NB * T_)   // 8192 rows
#define PSTR 72        // padded LDS row stride (elements) for 64-wide tiles

__device__ __forceinline__ float bf2f(u16 u) {
    union { u32 i; float f; } v; v.i = ((u32)u) << 16; return v.f;
}
// manual RTNE round (4 VALU ops; faster than the compiler's scalar cast path)
__device__ __forceinline__ u16 f2bf(float f) {
    union { float fl; u32 i; } v; v.fl = f;
    u32 r = v.i + 0x7fff + ((v.i >> 16) & 1);
    return (u16)(r >> 16);
}

// async global->LDS, 16B per lane; lds base must be wave-uniform
__device__ __forceinline__ void gl_lds16(const u16* g, u16* l) {
    __builtin_amdgcn_global_load_lds((const __attribute__((address_space(1))) void*)g,
                                     (__attribute__((address_space(3))) void*)l,
                                     16, 0, 0);
}

// ---------------------------------------------------------- dtype detector
__device__ __forceinline__ int detect_f32(const u16* p) {
    int weird = 0;
    const int lane = threadIdx.x & 63;
    #pragma unroll
    for (int i = 0; i < 4; ++i) {
        const u16 u = p[lane * 4 + i];
        const int e = (u >> 7) & 0xFF;
        weird += (e == 0xFF || (e >= 0x01 && e <= 0x3F) || (e >= 0xC0 && e <= 0xFE));
    }
    #pragma unroll
    for (int off = 32; off; off >>= 1) weird += __shfl_xor(weird, off);
    return weird >= 16;
}

// int32/int64-tolerant sequence-length read
__device__ __forceinline__ int read_len(const void* raw, int b) {
    const int* a32 = (const int*)raw;
    bool ok32 = true;
    #pragma unroll
    for (int i = 0; i < NB; ++i) {
        const int v = a32[i];
        if (v < 1 || v > T_) ok32 = false;
    }
    int v = ok32 ? a32[b] : (int)((const long long*)raw)[b];
    return min(max(v, 1), T_);
}

// ---------------------------------------------------------------- LayerNorm
__global__ __launch_bounds__(256) void ln_kernel(const void* __restrict__ xraw,
                                                 const void* __restrict__ graw,
                                                 const void* __restrict__ braw,
                                                 u16* __restrict__ h) {
    const int row = blockIdx.x;
    const int tid = threadIdx.x;
    const int isf = detect_f32((const u16*)xraw);

    float xv[4];
    if (isf) {
        const float* xr = (const float*)xraw + (size_t)row * D_;
        *(float4*)xv = *(const float4*)&xr[tid * 4];
    } else {
        const u16* xr = (const u16*)xraw + (size_t)row * D_;
        u16 loc[4] __attribute__((aligned(8)));
        *(uint2*)loc = *(const uint2*)&xr[tid * 4];
        #pragma unroll
        for (int i = 0; i < 4; ++i) xv[i] = bf2f(loc[i]);
    }

    float s = xv[0] + xv[1] + xv[2] + xv[3];
    float q = xv[0]*xv[0] + xv[1]*xv[1] + xv[2]*xv[2] + xv[3]*xv[3];

    #pragma unroll
    for (int off = 32; off; off >>= 1) {
        s += __shfl_xor(s, off);
        q += __shfl_xor(q, off);
    }
    __shared__ float red[8];
    const int wave = tid >> 6, lane = tid & 63;
    if (lane == 0) { red[wave] = s; red[4 + wave] = q; }
    __syncthreads();
    s = red[0] + red[1] + red[2] + red[3];
    q = red[4] + red[5] + red[6] + red[7];

    const float mean = s * (1.0f / D_);
    const float var  = q * (1.0f / D_) - mean * mean;
    const float rs   = rsqrtf(var + 1e-5f);

    u16 o[4] __attribute__((aligned(8)));
    #pragma unroll
    for (int i = 0; i < 4; ++i) {
        const int c = tid * 4 + i;
        const float gv = isf ? ((const float*)graw)[c] : bf2f(((const u16*)graw)[c]);
        const float bv = isf ? ((const float*)braw)[c] : bf2f(((const u16*)braw)[c]);
        o[i] = f2bf((xv[i] - mean) * rs * gv + bv);
    }
    *(uint2*)&h[(size_t)row * D_ + tid * 4] = *(uint2*)o;
}

// ------------------------------------------------- weight transpose+convert
// 4 weights in one launch (blockIdx.z selects). Wt[n][k] (bf16) from W[k][n].
__global__ __launch_bounds__(256) void wconv4_kernel(const void* __restrict__ W0,
                                                     const void* __restrict__ W1,
                                                     const void* __restrict__ W2,
                                                     const void* __restrict__ W3,
                                                     u16* __restrict__ Wt0,
                                                     u16* __restrict__ Wt1,
                                                     u16* __restrict__ Wt2,
                                                     u16* __restrict__ Wt3) {
    __shared__ u16 tile[64][PSTR];
    const int z = blockIdx.z;
    const void* Wraw = (z == 0) ? W0 : (z == 1) ? W1 : (z == 2) ? W2 : W3;
    u16* Wt          = (z == 0) ? Wt0 : (z == 1) ? Wt1 : (z == 2) ? Wt2 : Wt3;
    const int isf = detect_f32((const u16*)Wraw);
    const int n0 = blockIdx.x * 64;
    const int k0 = blockIdx.y * 64;
    const int tid = threadIdx.x;
    const int tr  = tid >> 2;          // 0..63
    const int tc  = (tid & 3) * 16;    // 0,16,32,48

    if (isf) {
        const float* W = (const float*)Wraw;
        #pragma unroll
        for (int i = 0; i < 16; ++i)
            tile[tc + i][tr] = f2bf(W[(size_t)(k0 + tr) * D_ + n0 + tc + i]);
    } else {
        const u16* W = (const u16*)Wraw;
        #pragma unroll
        for (int i = 0; i < 16; ++i)
            tile[tc + i][tr] = W[(size_t)(k0 + tr) * D_ + n0 + tc + i];
    }
    __syncthreads();
    *(uint4*)&Wt[(size_t)(n0 + tr) * D_ + k0 + tc]     = *(uint4*)&tile[tr][tc];
    *(uint4*)&Wt[(size_t)(n0 + tr) * D_ + k0 + tc + 8] = *(uint4*)&tile[tr][tc + 8];
}

// single-weight variant (fallback path)
__global__ __launch_bounds__(256) void wconv_kernel(const void* __restrict__ Wraw,
                                                    u16* __restrict__ Wt) {
    __shared__ u16 tile[64][PSTR];
    const int isf = detect_f32((const u16*)Wraw);
    const int n0 = blockIdx.x * 64;
    const int k0 = blockIdx.y * 64;
    const int tid = threadIdx.x;
    const int tr  = tid >> 2;
    const int tc  = (tid & 3) * 16;

    if (isf) {
        const float* W = (const float*)Wraw;
        #pragma unroll
        for (int i = 0; i < 16; ++i)
            tile[tc + i][tr] = f2bf(W[(size_t)(k0 + tr) * D_ + n0 + tc + i]);
    } else {
        const u16* W = (const u16*)Wraw;
        #pragma unroll
        for (int i = 0; i < 16; ++i)
            tile[tc + i][tr] = W[(size_t)(k0 + tr) * D_ + n0 + tc + i];
    }
    __syncthreads();
    *(uint4*)&Wt[(size_t)(n0 + tr) * D_ + k0 + tc]     = *(uint4*)&tile[tr][tc];
    *(uint4*)&Wt[(size_t)(n0 + tr) * D_ + k0 + tc + 8] = *(uint4*)&tile[tr][tc + 8];
}

// ---------------------------------------------------------------- RoPE table
// tab[t*32 + i] = {cos(t * 10000^(-i/32)), sin(...)}   (accurate library trig)
__global__ __launch_bounds__(256) void rope_kernel(float2* __restrict__ tab) {
    const int gid = blockIdx.x * 256 + threadIdx.x;   // 0..65535
    const int t = gid >> 5, i = gid & 31;
    const float inv = exp2f(-(float)i * 0.41524101186092f);
    const float ang = (float)t * inv;
    float sv, cv;
    sincosf(ang, &sv, &cv);
    tab[gid] = make_float2(cv, sv);
}

// --------------------------------------------------- V transpose (per head)
// vtmp (M, D) row-major -> vt (N, H, DH, T)
__global__ __launch_bounds__(256) void vtrans_kernel(const u16* __restrict__ vtmp,
                                                     u16* __restrict__ vt) {
    __shared__ u16 tile[64][PSTR];
    const int bh = blockIdx.y;
    const int b  = bh >> 4;
    const int hh = bh & 15;
    const int t0 = blockIdx.x * 64;
    const int tid = threadIdx.x;
    const int tr  = tid >> 2;          // 0..63
    const int tc  = (tid & 3) * 16;

    #pragma unroll
    for (int i = 0; i < 16; ++i)   // tile[d][t]
        tile[tc + i][tr] = vtmp[(size_t)(b * T_ + t0 + tr) * D_ + hh * DH + tc + i];
    __syncthreads();
    u16* dst = vt + (size_t)bh * DH * T_ + (size_t)tr * T_ + t0;
    *(uint4*)&dst[tc]     = *(uint4*)&tile[tr][tc];
    *(uint4*)&dst[tc + 8] = *(uint4*)&tile[tr][tc + 8];
}

// ---------------------------------------------------------------- fused QKV GEMM
// 128x128 tile over fused N=3072 (wtq|wtk|wtv contiguous). All outputs
// ROW-MAJOR (M, D). Q,K: table-based RoPE fused. V -> vtmp (transposed later).
__global__ __launch_bounds__(256) void qkv_kernel(const u16* __restrict__ A,
                                                  const u16* __restrict__ Wt3,
                                                  const void* __restrict__ Braw,
                                                  const void* __restrict__ bqr,
                                                  const void* __restrict__ bkr,
                                                  const void* __restrict__ bvr,
                                                  u16* __restrict__ qo,
                                                  u16* __restrict__ ko,
                                                  u16* __restrict__ vo,
                                                  const float2* __restrict__ tab) {
    __shared__ __align__(16) u16 As[128 * 32];
    __shared__ __align__(16) u16 Bs[128 * 32];

    const int tid   = threadIdx.x;
    const int wave  = tid >> 6;
    const int lane  = tid & 63;
    const int quad  = lane >> 4;
    const int lr    = lane & 15;
    const int ntile = blockIdx.x * 128;      // 0..2944
    const int mtile = blockIdx.y * 128;
    const int seg   = ntile >> 10;           // 0=Q 1=K 2=V

    const int isf = detect_f32((const u16*)Braw);

    const int srow = wave * 32 + (lane >> 2);
    const int scol = (lane & 3) * 8;
    const u16* aptr0 = A   + (size_t)(mtile + srow) * D_ + scol;
    const u16* aptr1 = A   + (size_t)(mtile + srow + 16) * D_ + scol;
    const u16* bptr0 = Wt3 + (size_t)(ntile + srow) * D_ + scol;
    const u16* bptr1 = Wt3 + (size_t)(ntile + srow + 16) * D_ + scol;
    u16* alds0 = As + wave * 1024;
    u16* alds1 = As + wave * 1024 + 512;
    u16* blds0 = Bs + wave * 1024;
    u16* blds1 = Bs + wave * 1024 + 512;

    const int mbase = (wave >> 1) * 64;
    const int nbase = (wave & 1) * 64;

    f32x4 acc[4][4];
    #pragma unroll
    for (int m = 0; m < 4; ++m)
        #pragma unroll
        for (int n = 0; n < 4; ++n)
            acc[m][n] = (f32x4){0.f, 0.f, 0.f, 0.f};

    for (int k0 = 0; k0 < D_; k0 += 32) {
        gl_lds16(aptr0 + k0, alds0);
        gl_lds16(aptr1 + k0, alds1);
        gl_lds16(bptr0 + k0, blds0);
        gl_lds16(bptr1 + k0, blds1);
        __syncthreads();

        bf16x8 af[4], bfr[4];
        #pragma unroll
        for (int m = 0; m < 4; ++m)
            af[m] = *(const bf16x8*)&As[(mbase + m * 16 + lr) * 32 + quad * 8];
        #pragma unroll
        for (int n = 0; n < 4; ++n)
            bfr[n] = *(const bf16x8*)&Bs[(nbase + n * 16 + lr) * 32 + quad * 8];
        #pragma unroll
        for (int m = 0; m < 4; ++m)
            #pragma unroll
            for (int n = 0; n < 4; ++n)
                acc[m][n] = __builtin_amdgcn_mfma_f32_16x16x32_bf16(af[m], bfr[n], acc[m][n], 0, 0, 0);

        __syncthreads();
    }

    const void* biasraw = (seg == 0) ? bqr : (seg == 1) ? bkr : bvr;
    u16* out            = (seg == 0) ? qo  : (seg == 1) ? ko  : vo;
    const int nloc = (ntile & 1023) + nbase;

    #pragma unroll
    for (int m = 0; m < 4; ++m) {
        #pragma unroll
        for (int n = 0; n < 4; ++n) {
            const int ncl = nloc + n * 16 + lr;       // 0..1023 within segment
            const float bv = isf ? ((const float*)biasraw)[ncl]
                                 : bf2f(((const u16*)biasraw)[ncl]);
            #pragma unroll
            for (int r = 0; r < 4; ++r) {
                const int mrow = mtile + mbase + m * 16 + quad * 4 + r;
                float v = acc[m][n][r] + bv;
                if (seg < 2) {
                    const float other = __shfl_xor(v, 1);
                    const int d = ncl & (DH - 1);
                    const int t = mrow & (T_ - 1);
                    const float2 cs = tab[t * 32 + (d >> 1)];
                    v = (d & 1) ? (other * cs.y + v * cs.x) : (v * cs.x - other * cs.y);
                }
                out[(size_t)mrow * D_ + ncl] = f2bf(v);
            }
        }
    }
}

// ---------------------------------------------------------------- GEMM (m97 structure)
// mode 0: row-major store to out (format follows weight dtype)
// mode 1: scatter V TRANSPOSED (N,H,DH,T)            [fallback path only]
// mode 2: scatter (N,H,T,DH) + RoPE (Q,K), sincosf   [fallback path only]
__global__ __launch_bounds__(256) void gemm128_kernel(const u16* __restrict__ A,
                                                      const u16* __restrict__ Bt,
                                                      const void* __restrict__ Braw,
                                                      const void* __restrict__ biasraw,
                                                      void* __restrict__ out,
                                                      const int mode) {
    __shared__ __align__(16) u16 As[128 * 32];
    __shared__ __align__(16) u16 Bs[128 * 32];

    const int tid   = threadIdx.x;
    const int wave  = tid >> 6;
    const int lane  = tid & 63;
    const int quad  = lane >> 4;
    const int lr    = lane & 15;
    const int ntile = blockIdx.x * 128;
    const int mtile = blockIdx.y * 128;

    const int isf = detect_f32((const u16*)Braw);

    const int srow = wave * 32 + (lane >> 2);
    const int scol = (lane & 3) * 8;
    const u16* aptr0 = A  + (size_t)(mtile + srow) * D_ + scol;
    const u16* aptr1 = A  + (size_t)(mtile + srow + 16) * D_ + scol;
    const u16* bptr0 = Bt + (size_t)(ntile + srow) * D_ + scol;
    const u16* bptr1 = Bt + (size_t)(ntile + srow + 16) * D_ + scol;
    u16* alds0 = As + wave * 1024;
    u16* alds1 = As + wave * 1024 + 512;
    u16* blds0 = Bs + wave * 1024;
    u16* blds1 = Bs + wave * 1024 + 512;

    const int mbase = (wave >> 1) * 64;
    const int nbase = (wave & 1) * 64;

    f32x4 acc[4][4];
    #pragma unroll
    for (int m = 0; m < 4; ++m)
        #pragma unroll
        for (int n = 0; n < 4; ++n)
            acc[m][n] = (f32x4){0.f, 0.f, 0.f, 0.f};

    for (int k0 = 0; k0 < D_; k0 += 32) {
        gl_lds16(aptr0 + k0, alds0);
        gl_lds16(aptr1 + k0, alds1);
        gl_lds16(bptr0 + k0, blds0);
        gl_lds16(bptr1 + k0, blds1);
        __syncthreads();

        bf16x8 af[4], bfr[4];
        #pragma unroll
        for (int m = 0; m < 4; ++m)
            af[m] = *(const bf16x8*)&As[(mbase + m * 16 + lr) * 32 + quad * 8];
        #pragma unroll
        for (int n = 0; n < 4; ++n)
            bfr[n] = *(const bf16x8*)&Bs[(nbase + n * 16 + lr) * 32 + quad * 8];
        #pragma unroll
        for (int m = 0; m < 4; ++m)
            #pragma unroll
            for (int n = 0; n < 4; ++n)
                acc[m][n] = __builtin_amdgcn_mfma_f32_16x16x32_bf16(af[m], bfr[n], acc[m][n], 0, 0, 0);

        __syncthreads();
    }

    #pragma unroll
    for (int m = 0; m < 4; ++m) {
        #pragma unroll
        for (int n = 0; n < 4; ++n) {
            const int ncol = ntile + nbase + n * 16 + lr;
            const float bv = isf ? ((const float*)biasraw)[ncol]
                                 : bf2f(((const u16*)biasraw)[ncol]);
            #pragma unroll
            for (int r = 0; r < 4; ++r) {
                const int mrow = mtile + mbase + m * 16 + quad * 4 + r;
                float v = acc[m][n][r] + bv;
                if (mode == 2) {
                    const float other = __shfl_xor(v, 1);
                    const int d = ncol & (DH - 1);
                    const int t = mrow & (T_ - 1);
                    const int i = d >> 1;
                    const float inv = exp2f(-(float)i * 0.41524101186092f);
                    const float ang = (float)t * inv;
                    float sv, cv;
                    __sincosf(ang, &sv, &cv);
                    v = (d & 1) ? (other * sv + v * cv) : (v * cv - other * sv);
                }
                const int d  = ncol & (DH - 1);
                const int hh = ncol >> 6;
                const int t  = mrow & (T_ - 1);
                const int bb = mrow >> 11;
                if (mode == 0) {
                    if (isf) ((float*)out)[(size_t)mrow * D_ + ncol] = v;
                    else     ((u16*)out)[(size_t)mrow * D_ + ncol] = f2bf(v);
                } else if (mode == 1) {
                    ((u16*)out)[(((size_t)(bb * H_ + hh) * DH) + d) * T_ + t] = f2bf(v);
                } else {
                    ((u16*)out)[(((size_t)(bb * H_ + hh) * T_) + t) * DH + d] = f2bf(v);
                }
            }
        }
    }
}

// ---------------------------------------------------------------- GEMM (no-wt fallback)
__global__ __launch_bounds__(256) void gemm_kernel(const u16* __restrict__ A,
                                                   const void* __restrict__ Braw,
                                                   const void* __restrict__ biasraw,
                                                   void* __restrict__ out,
                                                   const int mode) {
    __shared__ __align__(16) u16 As[128 * 32];
    __shared__ __align__(16) u16 Bs[64 * 32];

    const int tid   = threadIdx.x;
    const int ntile = blockIdx.x * 64;
    const int mtile = blockIdx.y * 128;
    const int wave  = tid >> 6;
    const int lane  = tid & 63;
    const int quad  = lane >> 4;
    const int lr    = lane & 15;

    const int isf = detect_f32((const u16*)Braw);
    const float* Bf = (const float*)Braw;
    const u16*   Bu = (const u16*)Braw;

    f32x4 acc[2][4];
    #pragma unroll
    for (int s = 0; s < 2; ++s)
        #pragma unroll
        for (int n = 0; n < 4; ++n)
            acc[s][n] = (f32x4){0.f, 0.f, 0.f, 0.f};

    const int ar  = tid >> 1;
    const int akb = (tid & 1) * 16;
    const int bn  = tid & 63;
    const int bkb = (tid >> 6) * 8;
    const u16* Arow = A + (size_t)(mtile + ar) * D_ + akb;
    const size_t bcol0 = (size_t)bkb * D_ + ntile + bn;

    for (int k0 = 0; k0 < D_; k0 += 32) {
        *(uint4*)&As[ar * 32 + akb]     = *(const uint4*)(Arow + k0);
        *(uint4*)&As[ar * 32 + akb + 8] = *(const uint4*)(Arow + k0 + 8);
        {
            u16 tmp[8] __attribute__((aligned(16)));
            if (isf) {
                #pragma unroll
                for (int j = 0; j < 8; ++j) tmp[j] = f2bf(Bf[bcol0 + (size_t)(k0 + j) * D_]);
            } else {
                #pragma unroll
                for (int j = 0; j < 8; ++j) tmp[j] = Bu[bcol0 + (size_t)(k0 + j) * D_];
            }
            *(uint4*)&Bs[bn * 32 + bkb] = *(uint4*)tmp;
        }
        __syncthreads();

        const int mbase = wave * 32;
        bf16x8 af0 = *(const bf16x8*)&As[(mbase +      lr) * 32 + quad * 8];
        bf16x8 af1 = *(const bf16x8*)&As[(mbase + 16 + lr) * 32 + quad * 8];
        #pragma unroll
        for (int nt = 0; nt < 4; ++nt) {
            bf16x8 bf = *(const bf16x8*)&Bs[(nt * 16 + lr) * 32 + quad * 8];
            acc[0][nt] = __builtin_amdgcn_mfma_f32_16x16x32_bf16(af0, bf, acc[0][nt], 0, 0, 0);
            acc[1][nt] = __builtin_amdgcn_mfma_f32_16x16x32_bf16(af1, bf, acc[1][nt], 0, 0, 0);
        }
        __syncthreads();
    }

    #pragma unroll
    for (int s2 = 0; s2 < 2; ++s2) {
        #pragma unroll
        for (int nt = 0; nt < 4; ++nt) {
            const int ncol = ntile + nt * 16 + lr;
            const float bv = isf ? ((const float*)biasraw)[ncol]
                                 : bf2f(((const u16*)biasraw)[ncol]);
            #pragma unroll
            for (int r = 0; r < 4; ++r) {
                const int mrow = mtile + wave * 32 + s2 * 16 + quad * 4 + r;
                float v = acc[s2][nt][r] + bv;
                if (mode == 2) {
                    const float other = __shfl_xor(v, 1);
                    const int d = ncol & (DH - 1);
                    const int t = mrow & (T_ - 1);
                    const int i = d >> 1;
                    const float inv = exp2f(-(float)i * 0.41524101186092f);
                    const float ang = (float)t * inv;
                    const float cv = cosf(ang), sv = sinf(ang);
                    v = (d & 1) ? (other * sv + v * cv) : (v * cv - other * sv);
                }
                const int d  = ncol & (DH - 1);
                const int hh = ncol >> 6;
                const int t  = mrow & (T_ - 1);
                const int bb = mrow >> 11;
                if (mode == 0) {
                    if (isf) ((float*)out)[(size_t)mrow * D_ + ncol] = v;
                    else     ((u16*)out)[(size_t)mrow * D_ + ncol] = f2bf(v);
                } else if (mode == 1) {
                    ((u16*)out)[(((size_t)(bb * H_ + hh) * DH) + d) * T_ + t] = f2bf(v);
                } else {
                    ((u16*)out)[(((size_t)(bb * H_ + hh) * T_) + t) * DH + d] = f2bf(v);
                }
            }
        }
    }
}

// ---------------------------------------------------------------- attention
// MFMA flash attention, FIXED-MAX softmax (cap-tanh folded):
//   p = exp2(C2 * rcp(z+1)), z = exp2(s*C1)   -- raw v_exp_f32/v_rcp_f32 only
// Single K/V LDS buffer + register prefetch (T14): next tile's global loads
// issue at loop top, land via ds_write after PV (barrier-protected).
// 2 barriers/tile (0 on last tile). Softmax->PV has NO barrier: Ps rows are
// wave-private (softmax writes rows wave*16..+15; PV A-frag reads the same).
// LDS 27.6 KB -> ~5 blocks/CU for latency hiding.
// rowmajor=1: Q/K are (M, D) row-major; rowmajor=0: (N,H,T,DH).
__global__ __launch_bounds__(256) void attn_kernel(const u16* __restrict__ Q,
                                                   const u16* __restrict__ K,
                                                   const u16* __restrict__ Vt,
                                                   const void* __restrict__ lensraw,
                                                   u16* __restrict__ ctx,
                                                   const int rowmajor) {
    __shared__ __align__(16) u16 Ps[64 * PSTR];    // Q staging, then P tile
    __shared__ __align__(16) u16 Ks[64 * PSTR];
    __shared__ __align__(16) u16 Vts[64 * PSTR];   // [dim][key]

    const int tid  = threadIdx.x;
    const int wave = tid >> 6;
    const int lane = tid & 63;
    const int quad = lane >> 4;
    const int lr   = lane & 15;
    const int bh   = blockIdx.y;
    const int qs   = blockIdx.x * 64;
    const int b    = bh >> 4;
    const int hh   = bh & 15;
    const int len  = read_len(lensraw, b);

    const size_t qkstride = rowmajor ? (size_t)D_ : (size_t)DH;
    const size_t qkoff    = rowmajor ? ((size_t)b * T_ * D_ + hh * DH)
                                     : ((size_t)bh * T_ * DH);
    const u16* Qp = Q + qkoff;
    const u16* Kp = K + qkoff;
    const u16* Vb = Vt + (size_t)bh * DH * T_;

    const int srow = tid >> 2;
    const int scb  = (tid & 3) * 16;

    // Q staging (wave-private rows) + K/V tile 0
    *(uint4*)&Ps[srow * PSTR + scb]     = *(const uint4*)&Qp[(size_t)(qs + srow) * qkstride + scb];
    *(uint4*)&Ps[srow * PSTR + scb + 8] = *(const uint4*)&Qp[(size_t)(qs + srow) * qkstride + scb + 8];
    {
        uint4 k0 = *(const uint4*)&Kp[(size_t)srow * qkstride + scb];
        uint4 k1 = *(const uint4*)&Kp[(size_t)srow * qkstride + scb + 8];
        uint4 v0 = *(const uint4*)&Vb[(size_t)srow * T_ + scb];
        uint4 v1 = *(const uint4*)&Vb[(size_t)srow * T_ + scb + 8];
        *(uint4*)&Ks[srow * PSTR + scb]      = k0;
        *(uint4*)&Ks[srow * PSTR + scb + 8]  = k1;
        *(uint4*)&Vts[srow * PSTR + scb]     = v0;
        *(uint4*)&Vts[srow * PSTR + scb + 8] = v1;
    }
    __syncthreads();
    const bf16x8 qa0 = *(const bf16x8*)&Ps[(wave * 16 + lr) * PSTR + quad * 8];
    const bf16x8 qa1 = *(const bf16x8*)&Ps[(wave * 16 + lr) * PSTR + 32 + quad * 8];

    f32x4 acc[4];
    float l_loc[4] = {0.f, 0.f, 0.f, 0.f};
    #pragma unroll
    for (int nt = 0; nt < 4; ++nt) acc[nt] = (f32x4){0.f, 0.f, 0.f, 0.f};

    const int smax = min(qs + 63, len - 1);
    const int ktn  = smax / 64 + 1;
    const int prow = wave * 16 + quad * 4;

    const float C1 = 1.44269504f / 120.0f;   // log2e / 120
    const float C2 = -60.0f * 1.44269504f;   // -60 * log2e

    uint4 kr0, kr1, vr0, vr1;
    for (int kt = 0; kt < ktn; ++kt) {
        const int ks = kt * 64;
        const bool havenext = (kt + 1 < ktn);   // block-uniform

        // register prefetch of next tile (latency hides under QK+SM+PV)
        if (havenext) {
            const int ns = ks + 64;
            kr0 = *(const uint4*)&Kp[(size_t)(ns + srow) * qkstride + scb];
            kr1 = *(const uint4*)&Kp[(size_t)(ns + srow) * qkstride + scb + 8];
            vr0 = *(const uint4*)&Vb[(size_t)srow * T_ + ns + scb];
            vr1 = *(const uint4*)&Vb[(size_t)srow * T_ + ns + scb + 8];
        }

        // QK^T
        f32x4 s[4];
        #pragma unroll
        for (int nt = 0; nt < 4; ++nt) s[nt] = (f32x4){0.f, 0.f, 0.f, 0.f};
        __builtin_amdgcn_s_setprio(1);
        #pragma unroll
        for (int nt = 0; nt < 4; ++nt) {
            bf16x8 kb0 = *(const bf16x8*)&Ks[(nt * 16 + lr) * PSTR + quad * 8];
            bf16x8 kb1 = *(const bf16x8*)&Ks[(nt * 16 + lr) * PSTR + 32 + quad * 8];
            s[nt] = __builtin_amdgcn_mfma_f32_16x16x32_bf16(qa0, kb0, s[nt], 0, 0, 0);
            s[nt] = __builtin_amdgcn_mfma_f32_16x16x32_bf16(qa1, kb1, s[nt], 0, 0, 0);
        }
        __builtin_amdgcn_s_setprio(0);

        // fixed-max softmax; masking only on diagonal / len-boundary tiles
        const bool need_mask = (ks == qs) || (ks + 63 >= len);
        if (!need_mask) {
            #pragma unroll
            for (int r = 0; r < 4; ++r) {
                #pragma unroll
                for (int nt = 0; nt < 4; ++nt) {
                    const float z = __builtin_amdgcn_exp2f(s[nt][r] * C1);
                    const float p = __builtin_amdgcn_exp2f(C2 * __builtin_amdgcn_rcpf(z + 1.0f));
                    l_loc[r] += p;
                    Ps[(prow + r) * PSTR + nt * 16 + lr] = f2bf(p);
                }
            }
        } else {
            #pragma unroll
            for (int r = 0; r < 4; ++r) {
                const int trow = qs + prow + r;
                #pragma unroll
                for (int nt = 0; nt < 4; ++nt) {
                    const float z = __builtin_amdgcn_exp2f(s[nt][r] * C1);
                    float p = __builtin_amdgcn_exp2f(C2 * __builtin_amdgcn_rcpf(z + 1.0f));
                    const int col = ks + nt * 16 + lr;
                    p = (col > trow || col >= len) ? 0.f : p;
                    l_loc[r] += p;
                    Ps[(prow + r) * PSTR + nt * 16 + lr] = f2bf(p);
                }
            }
        }
        // no barrier: Ps rows are wave-private

        // PV
        bf16x8 pa0 = *(const bf16x8*)&Ps[(wave * 16 + lr) * PSTR + quad * 8];
        bf16x8 pa1 = *(const bf16x8*)&Ps[(wave * 16 + lr) * PSTR + 32 + quad * 8];
        __builtin_amdgcn_s_setprio(1);
        #pragma unroll
        for (int nt = 0; nt < 4; ++nt) {
            bf16x8 vb0 = *(const bf16x8*)&Vts[(nt * 16 + lr) * PSTR + quad * 8];
            bf16x8 vb1 = *(const bf16x8*)&Vts[(nt * 16 + lr) * PSTR + 32 + quad * 8];
            acc[nt] = __builtin_amdgcn_mfma_f32_16x16x32_bf16(pa0, vb0, acc[nt], 0, 0, 0);
            acc[nt] = __builtin_amdgcn_mfma_f32_16x16x32_bf16(pa1, vb1, acc[nt], 0, 0, 0);
        }
        __builtin_amdgcn_s_setprio(0);

        if (havenext) {
            __syncthreads();   // all reads of Ks/Vts done before overwrite
            *(uint4*)&Ks[srow * PSTR + scb]      = kr0;
            *(uint4*)&Ks[srow * PSTR + scb + 8]  = kr1;
            *(uint4*)&Vts[srow * PSTR + scb]     = vr0;
            *(uint4*)&Vts[srow * PSTR + scb + 8] = vr1;
            __syncthreads();   // new tile visible
        }
    }

    // epilogue: reduce l across the 16 lanes of each row group, write ctx
    #pragma unroll
    for (int r = 0; r < 4; ++r) {
        float l = l_loc[r];
        #pragma unroll
        for (int off = 1; off < 16; off <<= 1) l += __shfl_xor(l, off);
        const float invl = (l > 0.f) ? (1.0f / l) : 0.f;
        const int qrow = prow + r;
        #pragma unroll
        for (int nt = 0; nt < 4; ++nt) {
            ctx[(size_t)(b * T_ + qs + qrow) * D_ + hh * DH + nt * 16 + lr] =
                f2bf(acc[nt][r] * invl);
        }
    }
}

// ---------------------------------------------------------------- launch
extern "C" void kernel_launch(void* const* d_in, const int* in_sizes, int n_in,
                              void* d_out, int out_size, void* d_ws, size_t ws_size,
                              hipStream_t stream) {
    // ws layout: [h][q][k][vt : 16MB each][wtq|wtk|wtv|wto : 2MB each]
    //            [vtmp 16MB][rope table 512KB]
    u16* h = (u16*)d_ws;
    const size_t MD = (size_t)M_ * D_;
    const size_t WD = (size_t)D_ * D_;
    u16* q  = h + MD;
    u16* k  = q + MD;
    u16* vt = k + MD;
    const bool havewt  = ws_size >= (4 * MD + 4 * WD) * sizeof(u16);
    const bool havebig = ws_size >= (5 * MD + 4 * WD) * sizeof(u16)
                                    + (size_t)T_ * 32 * sizeof(float2);
    u16* wtq = havewt ? (vt + MD)  : nullptr;
    u16* wtk = havewt ? (wtq + WD) : nullptr;
    u16* wtv = havewt ? (wtk + WD) : nullptr;
    u16* wto = havewt ? (wtv + WD) : nullptr;
    u16* vtmp = havebig ? (wto + WD) : nullptr;
    float2* tab = havebig ? (float2*)(vtmp + MD) : nullptr;

    ln_kernel<<<M_, 256, 0, stream>>>(d_in[0], d_in[1], d_in[2], h);

    if (havebig) {
        wconv4_kernel<<<dim3(D_ / 64, D_ / 64, 4), 256, 0, stream>>>(
            d_in[3], d_in[5], d_in[7], d_in[9], wtq, wtk, wtv, wto);
        rope_kernel<<<256, 256, 0, stream>>>(tab);

        qkv_kernel<<<dim3(3 * D_ / 128, M_ / 128), 256, 0, stream>>>(
            h, wtq, d_in[3], d_in[4], d_in[6], d_in[8], q, k, vtmp, tab);

        vtrans_kernel<<<dim3(T_ / 64, NB * H_), 256, 0, stream>>>(vtmp, vt);

        attn_kernel<<<dim3(T_ / 64, NB * H_), 256, 0, stream>>>(q, k, vt, d_in[13], h, 1);

        gemm128_kernel<<<dim3(D_ / 128, M_ / 128), 256, 0, stream>>>(
            h, wto, d_in[9], d_in[10], d_out, 0);
    } else if (havewt) {
        dim3 wgrid(D_ / 64, D_ / 64);
        wconv_kernel<<<wgrid, 256, 0, stream>>>(d_in[3], wtq);
        wconv_kernel<<<wgrid, 256, 0, stream>>>(d_in[5], wtk);
        wconv_kernel<<<wgrid, 256, 0, stream>>>(d_in[7], wtv);
        wconv_kernel<<<wgrid, 256, 0, stream>>>(d_in[9], wto);

        dim3 g128(D_ / 128, M_ / 128);
        gemm128_kernel<<<g128, 256, 0, stream>>>(h, wtq, d_in[3], d_in[4], q, 2);
        gemm128_kernel<<<g128, 256, 0, stream>>>(h, wtk, d_in[5], d_in[6], k, 2);
        gemm128_kernel<<<g128, 256, 0, stream>>>(h, wtv, d_in[7], d_in[8], vt, 1);

        attn_kernel<<<dim3(T_ / 64, NB * H_), 256, 0, stream>>>(q, k, vt, d_in[13], h, 0);

        gemm128_kernel<<<g128, 256, 0, stream>>>(h, wto, d_in[9], d_in[10], d_out, 0);
    } else {
        dim3 ggrid(D_ / 64, M_ / 128);
        gemm_kernel<<<ggrid, 256, 0, stream>>>(h, d_in[3], d_in[4], q, 2);
        gemm_kernel<<<ggrid, 256, 0, stream>>>(h, d_in[5], d_in[6], k, 2);
        gemm_kernel<<<ggrid, 256, 0, stream>>>(h, d_in[7], d_in[8], vt, 1);

        attn_kernel<<<dim3(T_ / 64, NB * H_), 256, 0, stream>>>(q, k, vt, d_in[13], h, 0);

        gemm_kernel<<<ggrid, 256, 0, stream>>>(h, d_in[9], d_in[10], d_out, 0);
    }
}